// Round 2
// baseline (78.362 us; speedup 1.0000x reference)
//
#include <hip/hip_runtime.h>
#include <hip/hip_bf16.h>

#define IN_CAPS 32
#define OUT_CAPS 10
#define OUT_DIM 16
#define NOUT 160      // OUT_CAPS*OUT_DIM
#define KDIM 288
#define BATCH 4096
#define KSTEPS 9      // 288/32
#define CTILES 10     // 160/16
#define USTR 169      // LDS row stride for u (169 mod 32 = 9, coprime w/ 32 -> conflict-free)

typedef __bf16 bf16x8 __attribute__((ext_vector_type(8)));
typedef float  f32x4  __attribute__((ext_vector_type(4)));

// ---------------------------------------------------------------------------
// prep_w: W f32 [32][288][160] -> bf16 in per-lane MFMA B-fragment order:
//   Wf[((n*9+ks)*10+ct)*512 + lane*8 + j] = W[n][ks*32+(lane>>4)*8+j][ct*16+(lane&15)]
// ---------------------------------------------------------------------------
__global__ __launch_bounds__(256) void prep_w(const float* __restrict__ W,
                                              __bf16* __restrict__ Wf) {
    int f = blockIdx.x * 256 + threadIdx.x;   // grid covers exactly 32*9*10*512
    int j    = f & 7;
    int l    = (f >> 3) & 63;
    int rest = f >> 9;
    int c    = rest % CTILES;
    int tnk  = rest / CTILES;
    int ks   = tnk % KSTEPS;
    int n    = tnk / KSTEPS;
    int k    = ks * 32 + (l >> 4) * 8 + j;
    int col  = c * 16 + (l & 15);
    Wf[f] = (__bf16)W[(n * KDIM + k) * NOUT + col];
}

// ---------------------------------------------------------------------------
// gemm_u: u[b][n][col] (bf16) = caps[b][n][:] dot W[n][:][col]
// Per wave: 64 rows x 160 cols, mfma_f32_16x16x32_bf16, no LDS, no barriers.
// ---------------------------------------------------------------------------
__global__ __launch_bounds__(256, 2) void gemm_u(const float* __restrict__ caps,
                                                 const __bf16* __restrict__ Wf,
                                                 __bf16* __restrict__ u) {
    const int n       = blockIdx.y;            // capsule 0..31
    const int wave    = threadIdx.x >> 6;      // 0..3
    const int lane    = threadIdx.x & 63;
    const int rowbase = (blockIdx.x * 4 + wave) * 64;   // 16 blocks * 4 waves * 64 = 4096
    const int lm      = lane & 15;
    const int lk      = lane >> 4;             // 0..3

    f32x4 acc[4][CTILES];
#pragma unroll
    for (int mt = 0; mt < 4; ++mt)
#pragma unroll
        for (int ct = 0; ct < CTILES; ++ct)
            acc[mt][ct] = (f32x4){0.f, 0.f, 0.f, 0.f};

    const __bf16* wfn = Wf + (size_t)n * (KSTEPS * CTILES * 512);

    for (int ks = 0; ks < KSTEPS; ++ks) {
        // A fragments: lane holds rows rowbase+mt*16+lm, k = ks*32 + lk*8 + j
        bf16x8 afr[4];
#pragma unroll
        for (int mt = 0; mt < 4; ++mt) {
            const float* src = caps + (size_t)(rowbase + mt * 16 + lm) * (IN_CAPS * KDIM)
                                    + n * KDIM + ks * 32 + lk * 8;
            f32x4 x0 = *(const f32x4*)(src);
            f32x4 x1 = *(const f32x4*)(src + 4);
            bf16x8 a;
            a[0] = (__bf16)x0[0]; a[1] = (__bf16)x0[1];
            a[2] = (__bf16)x0[2]; a[3] = (__bf16)x0[3];
            a[4] = (__bf16)x1[0]; a[5] = (__bf16)x1[1];
            a[6] = (__bf16)x1[2]; a[7] = (__bf16)x1[3];
            afr[mt] = a;
        }
        const __bf16* wks = wfn + (size_t)ks * (CTILES * 512) + lane * 8;
#pragma unroll
        for (int ct = 0; ct < CTILES; ++ct) {
            bf16x8 bfr = *(const bf16x8*)(wks + ct * 512);
#pragma unroll
            for (int mt = 0; mt < 4; ++mt)
                acc[mt][ct] = __builtin_amdgcn_mfma_f32_16x16x32_bf16(afr[mt], bfr, acc[mt][ct], 0, 0, 0);
        }
    }

    // C/D mapping (verified): col = lane&15, row = (lane>>4)*4 + reg
#pragma unroll
    for (int mt = 0; mt < 4; ++mt)
#pragma unroll
        for (int ct = 0; ct < CTILES; ++ct)
#pragma unroll
            for (int r = 0; r < 4; ++r) {
                int row = rowbase + mt * 16 + lk * 4 + r;
                int col = ct * 16 + lm;
                u[((size_t)row * IN_CAPS + n) * NOUT + col] = (__bf16)acc[mt][ct][r];
            }
}

// ---------------------------------------------------------------------------
// routing: one block per batch element. u[b] (32x160) -> LDS f32 (stride 169),
// then: c=softmax(b); s=c.u; v=squash(s); 3x { b+=u.v; c=softmax; s; v }.
// ---------------------------------------------------------------------------
__global__ __launch_bounds__(256) void routing(const __bf16* __restrict__ u,
                                               const float* __restrict__ bbias,
                                               float* __restrict__ out) {
    __shared__ float ul[IN_CAPS * USTR];          // 21632 B
    __shared__ float bl[IN_CAPS * OUT_CAPS];      // [n][o], n*10+o
    __shared__ float cs[IN_CAPS * OUT_CAPS];
    __shared__ float ss[NOUT];
    __shared__ float vs[NOUT];
    __shared__ float scale_s[OUT_CAPS];

    const int b = blockIdx.x;
    const int t = threadIdx.x;
    const __bf16* ub = u + (size_t)b * (IN_CAPS * NOUT);

    // load u[b] -> LDS f32, 8 bf16 per 16B chunk, 640 chunks
    for (int cc = t; cc < 640; cc += 256) {
        int n = cc / 20;             // 160/8 = 20 chunks per row
        int rem = cc - n * 20;
        uint4 raw = *(const uint4*)(ub + cc * 8);
        bf16x8 bv = __builtin_bit_cast(bf16x8, raw);
#pragma unroll
        for (int j = 0; j < 8; ++j) ul[n * USTR + rem * 8 + j] = (float)bv[j];
    }
    // init b_loc from bias input (320 entries > 256 threads: MUST stride — was the R1 bug)
    for (int p = t; p < IN_CAPS * OUT_CAPS; p += 256) bl[p] = bbias[p];
    __syncthreads();

    for (int it = 0; it < 4; ++it) {
        if (it > 0) {
            // agreement: bl[n][o] += sum_d u[n][o*16+d] * v[o*16+d]
            for (int p = t; p < IN_CAPS * OUT_CAPS; p += 256) {
                int n = p & 31;
                int o = p >> 5;
                float a = 0.f;
#pragma unroll
                for (int d = 0; d < 16; ++d)
                    a += ul[n * USTR + o * 16 + d] * vs[o * 16 + d];
                bl[n * 10 + o] += a;
            }
            __syncthreads();
        }
        // softmax over o per n
        if (t < IN_CAPS) {
            float m = bl[t * 10];
#pragma unroll
            for (int o = 1; o < 10; ++o) m = fmaxf(m, bl[t * 10 + o]);
            float e[10];
            float sum = 0.f;
#pragma unroll
            for (int o = 0; o < 10; ++o) { e[o] = __expf(bl[t * 10 + o] - m); sum += e[o]; }
            float inv = 1.0f / sum;
#pragma unroll
            for (int o = 0; o < 10; ++o) cs[t * 10 + o] = e[o] * inv;
        }
        __syncthreads();
        // s[o][d] = sum_n c[n][o] * u[n][o*16+d]
        if (t < NOUT) {
            int o = t >> 4;
            float acc = 0.f;
#pragma unroll
            for (int n = 0; n < IN_CAPS; ++n)
                acc += cs[n * 10 + o] * ul[n * USTR + t];
            ss[t] = acc;
        }
        __syncthreads();
        // squash scale per o
        if (t < OUT_CAPS) {
            float sq = 0.f;
#pragma unroll
            for (int d = 0; d < 16; ++d) { float x = ss[t * 16 + d]; sq += x * x; }
            scale_s[t] = sq / ((1.0f + sq) * sqrtf(sq));
        }
        __syncthreads();
        if (t < NOUT) vs[t] = scale_s[t >> 4] * ss[t];
        __syncthreads();
    }

    if (t < NOUT) out[(size_t)b * NOUT + t] = vs[t];
}

// ---------------------------------------------------------------------------
extern "C" void kernel_launch(void* const* d_in, const int* in_sizes, int n_in,
                              void* d_out, int out_size, void* d_ws, size_t ws_size,
                              hipStream_t stream) {
    const float* caps  = (const float*)d_in[0];   // [4096][32][288]
    const float* W     = (const float*)d_in[1];   // [32][288][160]
    const float* bbias = (const float*)d_in[2];   // [32][10]
    float* out = (float*)d_out;                   // [4096][10][16]

    __bf16* Wf = (__bf16*)d_ws;                               // 2,949,120 B
    __bf16* u  = (__bf16*)((char*)d_ws + 2949120);            // 41,943,040 B

    prep_w<<<dim3(5760), dim3(256), 0, stream>>>(W, Wf);      // 5760*256 = 1,474,560
    gemm_u<<<dim3(16, 32), dim3(256), 0, stream>>>(caps, Wf, u);
    routing<<<dim3(BATCH), dim3(256), 0, stream>>>(u, bbias, out);
}